// Round 1
// baseline (3243.107 us; speedup 1.0000x reference)
//
#include <hip/hip_runtime.h>
#include <math.h>

// Problem constants
#define B_  2
#define L_  2048
#define D_  1024
#define H_  16
#define R_  512
#define HD_ 64
#define M_  (B_*L_)          // 4096 rows
#define EPS_ 1e-5f

// ---------------------------------------------------------------------------
// LayerNorm: one block per row, 256 threads, float4 loads (D=1024=256*4)
// ---------------------------------------------------------------------------
__global__ __launch_bounds__(256) void ln_kernel(const float* __restrict__ x,
                                                 const float* __restrict__ g,
                                                 const float* __restrict__ b,
                                                 float* __restrict__ out) {
    int row = blockIdx.x;
    int t = threadIdx.x;
    const float4* xr = (const float4*)(x + (size_t)row * D_);
    float4 v = xr[t];
    float s  = v.x + v.y + v.z + v.w;
    float ss = v.x*v.x + v.y*v.y + v.z*v.z + v.w*v.w;
    #pragma unroll
    for (int o = 32; o > 0; o >>= 1) {
        s  += __shfl_down(s,  o);
        ss += __shfl_down(ss, o);
    }
    __shared__ float rs[4], rss[4];
    int wave = t >> 6, lane = t & 63;
    if (lane == 0) { rs[wave] = s; rss[wave] = ss; }
    __syncthreads();
    if (t == 0) {
        float a = 0.f, c = 0.f;
        for (int i = 0; i < 4; i++) { a += rs[i]; c += rss[i]; }
        rs[0] = a; rss[0] = c;
    }
    __syncthreads();
    float mean = rs[0] * (1.0f / D_);
    float var  = rss[0] * (1.0f / D_) - mean * mean;
    float inv  = rsqrtf(var + EPS_);
    float4 gv = ((const float4*)g)[t];
    float4 bv = ((const float4*)b)[t];
    float4 o;
    o.x = (v.x - mean) * inv * gv.x + bv.x;
    o.y = (v.y - mean) * inv * gv.y + bv.y;
    o.z = (v.z - mean) * inv * gv.z + bv.z;
    o.w = (v.w - mean) * inv * gv.w + bv.w;
    ((float4*)(out + (size_t)row * D_))[t] = o;
}

// ---------------------------------------------------------------------------
// Tiled fp32 GEMM: C[M,N] = A[M,K] @ W[K,N] + bias[N] (+res) (optional relu)
// BM=BN=64, BK=16, 256 threads, 4x4 outputs per thread.
// res may alias C (each element read-then-written by exactly one thread).
// ---------------------------------------------------------------------------
template<int RELU>
__global__ __launch_bounds__(256) void gemm_kernel(const float* __restrict__ A,
                                                   const float* __restrict__ W,
                                                   const float* __restrict__ bias,
                                                   const float* res,
                                                   float* C,
                                                   int M, int N, int K) {
    __shared__ float As[16][64];   // [k][m]
    __shared__ float Ws[16][64];   // [k][n]
    int t  = threadIdx.x;
    int tx = t & 15, ty = t >> 4;
    int bm = blockIdx.y * 64, bn = blockIdx.x * 64;

    // load indices: 1024 elems per tile, 4 per thread (float4)
    int ar = t >> 2;             // 0..63  (row in A tile)
    int ac = (t & 3) * 4;        // 0,4,8,12 (col in A tile)
    int wr = t >> 4;             // 0..15  (row in W tile)
    int wc = (t & 15) * 4;       // 0..60  (col in W tile)

    float acc[4][4] = {};

    for (int kt = 0; kt < K; kt += 16) {
        float4 av = *(const float4*)(A + (size_t)(bm + ar) * K + kt + ac);
        float4 wv = *(const float4*)(W + (size_t)(kt + wr) * N + bn + wc);
        __syncthreads();   // protect prev-iter LDS reads
        As[ac + 0][ar] = av.x;
        As[ac + 1][ar] = av.y;
        As[ac + 2][ar] = av.z;
        As[ac + 3][ar] = av.w;
        *(float4*)&Ws[wr][wc] = wv;
        __syncthreads();
        #pragma unroll
        for (int k = 0; k < 16; k++) {
            float4 a4 = *(const float4*)&As[k][ty * 4];
            float4 w4 = *(const float4*)&Ws[k][tx * 4];
            float a[4] = {a4.x, a4.y, a4.z, a4.w};
            float w[4] = {w4.x, w4.y, w4.z, w4.w};
            #pragma unroll
            for (int i = 0; i < 4; i++)
                #pragma unroll
                for (int j = 0; j < 4; j++)
                    acc[i][j] = fmaf(a[i], w[j], acc[i][j]);
        }
    }

    #pragma unroll
    for (int i = 0; i < 4; i++) {
        int r = bm + ty * 4 + i;
        #pragma unroll
        for (int j = 0; j < 4; j++) {
            int c = bn + tx * 4 + j;
            float v = acc[i][j] + bias[c];
            if (RELU) v = fmaxf(v, 0.0f);
            if (res) v += res[(size_t)r * N + c];
            C[(size_t)r * N + c] = v;
        }
    }
}

// ---------------------------------------------------------------------------
// Windowed-causal attention with rel-pos bias.
// rel_pos_bias masks to 0 <= q-k < R  ==> keys in [q-511, q].
// qkv layout: [m][3*D] rows; q at +h*HD, k at +D+h*HD, v at +2D+h*HD.
// One block (256 thr) per (b,h,q). ctx written as [b*L+q][h*HD+d].
// ---------------------------------------------------------------------------
__global__ __launch_bounds__(256) void attn_kernel(const float* __restrict__ qkv,
                                                   const float* __restrict__ res_pos,
                                                   float* __restrict__ ctx) {
    int q = blockIdx.x % L_;
    int h = (blockIdx.x / L_) % H_;
    int b = blockIdx.x / (L_ * H_);
    int t = threadIdx.x;

    __shared__ float sQ[HD_];
    __shared__ float sS[R_];
    __shared__ float red[8];
    __shared__ float rctx[4][HD_];

    const size_t row3 = (size_t)3 * D_;
    const float* qp = qkv + (size_t)(b * L_ + q) * row3 + h * HD_;
    if (t < HD_) sQ[t] = qp[t];
    __syncthreads();

    int klo = q - (R_ - 1); if (klo < 0) klo = 0;
    int nk = q - klo + 1;
    const float scale = 0.125f;   // 1/sqrt(64)

    float lmax = -1e30f;
    for (int j = t; j < nk; j += 256) {
        int key = klo + j;
        const float* kp = qkv + (size_t)(b * L_ + key) * row3 + D_ + h * HD_;
        float dot = 0.f;
        #pragma unroll
        for (int d = 0; d < HD_; d += 4) {
            float4 kv4 = *(const float4*)(kp + d);
            dot += sQ[d]*kv4.x + sQ[d+1]*kv4.y + sQ[d+2]*kv4.z + sQ[d+3]*kv4.w;
        }
        float s = dot * scale + res_pos[h * R_ + (q - key)];
        sS[j] = s;
        lmax = fmaxf(lmax, s);
    }
    #pragma unroll
    for (int o = 32; o > 0; o >>= 1) lmax = fmaxf(lmax, __shfl_down(lmax, o));
    int wave = t >> 6, lane = t & 63;
    if (lane == 0) red[wave] = lmax;
    __syncthreads();
    if (t == 0) {
        float m = red[0];
        for (int i = 1; i < 4; i++) m = fmaxf(m, red[i]);
        red[0] = m;
    }
    __syncthreads();
    float smax = red[0];

    float lsum = 0.f;
    for (int j = t; j < nk; j += 256) {
        float p = expf(sS[j] - smax);
        sS[j] = p;
        lsum += p;
    }
    #pragma unroll
    for (int o = 32; o > 0; o >>= 1) lsum += __shfl_down(lsum, o);
    if (lane == 0) red[4 + wave] = lsum;
    __syncthreads();
    if (t == 0) {
        float s2 = 0.f;
        for (int i = 0; i < 4; i++) s2 += red[4 + i];
        red[4] = s2;
    }
    __syncthreads();
    float inv = 1.0f / red[4];

    int d = t & 63, g = t >> 6;
    float acc = 0.f;
    for (int j = g; j < nk; j += 4) {
        const float* vp = qkv + (size_t)(b * L_ + klo + j) * row3 + 2 * D_ + h * HD_;
        acc += sS[j] * vp[d];
    }
    rctx[g][d] = acc;
    __syncthreads();
    if (t < HD_) {
        float c = (rctx[0][t] + rctx[1][t] + rctx[2][t] + rctx[3][t]) * inv;
        ctx[(size_t)(b * L_ + q) * D_ + h * HD_ + t] = c;
    }
}

// ---------------------------------------------------------------------------
// Orchestration.
// ws layout (floats): A[0, M*D) ; Bq[M*D, 4*M*D) ; extra[4*M*D, 5*M*D)
//   A  : xn -> ctx -> xn2
//   Bq : qkv; after attention, h1 = [M*D, 5*M*D) overlays Bq+extra
//   d_out doubles as x1 (residual read in-place in final GEMM).
// Needs ws_size >= 5*M*D*4 = 80 MiB.
// ---------------------------------------------------------------------------
extern "C" void kernel_launch(void* const* d_in, const int* in_sizes, int n_in,
                              void* d_out, int out_size, void* d_ws, size_t ws_size,
                              hipStream_t stream) {
    const float* x      = (const float*)d_in[0];
    const float* res_pos= (const float*)d_in[1];
    const float* w_qkv  = (const float*)d_in[2];
    const float* b_qkv  = (const float*)d_in[3];
    const float* w_out  = (const float*)d_in[4];
    const float* b_out  = (const float*)d_in[5];
    const float* w1     = (const float*)d_in[6];
    const float* b1     = (const float*)d_in[7];
    const float* w2     = (const float*)d_in[8];
    const float* b2     = (const float*)d_in[9];
    const float* ln1_g  = (const float*)d_in[10];
    const float* ln1_b  = (const float*)d_in[11];
    const float* ln2_g  = (const float*)d_in[12];
    const float* ln2_b  = (const float*)d_in[13];
    float* out = (float*)d_out;
    float* ws  = (float*)d_ws;

    float* A  = ws;                      // M*D
    float* Bq = ws + (size_t)M_ * D_;    // M*3D (qkv)
    float* h1 = ws + (size_t)M_ * D_;    // M*4D (overlays Bq + extra)

    // 1. xn = LN1(x)
    ln_kernel<<<M_, 256, 0, stream>>>(x, ln1_g, ln1_b, A);
    // 2. qkv = xn @ w_qkv + b_qkv
    gemm_kernel<0><<<dim3(3 * D_ / 64, M_ / 64), 256, 0, stream>>>(
        A, w_qkv, b_qkv, nullptr, Bq, M_, 3 * D_, D_);
    // 3. ctx = windowed attention (writes into A)
    attn_kernel<<<B_ * H_ * L_, 256, 0, stream>>>(Bq, res_pos, A);
    // 4. x1 = x + ctx @ w_out + b_out   (into d_out)
    gemm_kernel<0><<<dim3(D_ / 64, M_ / 64), 256, 0, stream>>>(
        A, w_out, b_out, x, out, M_, D_, D_);
    // 5. xn2 = LN2(x1)  (into A)
    ln_kernel<<<M_, 256, 0, stream>>>(out, ln2_g, ln2_b, A);
    // 6. h1 = relu(xn2 @ w1 + b1)
    gemm_kernel<1><<<dim3(4 * D_ / 64, M_ / 64), 256, 0, stream>>>(
        A, w1, b1, nullptr, h1, M_, 4 * D_, D_);
    // 7. out = x1 + h1 @ w2 + b2   (in-place residual on d_out)
    gemm_kernel<0><<<dim3(D_ / 64, M_ / 64), 256, 0, stream>>>(
        h1, w2, b2, out, out, M_, D_, 4 * D_);
}

// Round 2
// 2302.446 us; speedup vs baseline: 1.4085x; 1.4085x over previous
//
#include <hip/hip_runtime.h>
#include <math.h>

// Problem constants
#define B_  2
#define L_  2048
#define D_  1024
#define H_  16
#define R_  512
#define HD_ 64
#define M_  (B_*L_)          // 4096 rows
#define EPS_ 1e-5f

// ---------------------------------------------------------------------------
// LayerNorm: one block per row, 256 threads, float4 loads (D=1024=256*4)
// ---------------------------------------------------------------------------
__global__ __launch_bounds__(256) void ln_kernel(const float* __restrict__ x,
                                                 const float* __restrict__ g,
                                                 const float* __restrict__ b,
                                                 float* __restrict__ out) {
    int row = blockIdx.x;
    int t = threadIdx.x;
    const float4* xr = (const float4*)(x + (size_t)row * D_);
    float4 v = xr[t];
    float s  = v.x + v.y + v.z + v.w;
    float ss = v.x*v.x + v.y*v.y + v.z*v.z + v.w*v.w;
    #pragma unroll
    for (int o = 32; o > 0; o >>= 1) {
        s  += __shfl_down(s,  o);
        ss += __shfl_down(ss, o);
    }
    __shared__ float rs[4], rss[4];
    int wave = t >> 6, lane = t & 63;
    if (lane == 0) { rs[wave] = s; rss[wave] = ss; }
    __syncthreads();
    if (t == 0) {
        float a = 0.f, c = 0.f;
        for (int i = 0; i < 4; i++) { a += rs[i]; c += rss[i]; }
        rs[0] = a; rss[0] = c;
    }
    __syncthreads();
    float mean = rs[0] * (1.0f / D_);
    float var  = rss[0] * (1.0f / D_) - mean * mean;
    float inv  = rsqrtf(var + EPS_);
    float4 gv = ((const float4*)g)[t];
    float4 bv = ((const float4*)b)[t];
    float4 o;
    o.x = (v.x - mean) * inv * gv.x + bv.x;
    o.y = (v.y - mean) * inv * gv.y + bv.y;
    o.z = (v.z - mean) * inv * gv.z + bv.z;
    o.w = (v.w - mean) * inv * gv.w + bv.w;
    ((float4*)(out + (size_t)row * D_))[t] = o;
}

// ---------------------------------------------------------------------------
// Tiled fp32 GEMM: C[M,N] = A[M,K] @ W[K,N] + bias[N] (+res) (optional relu)
// BM=BN=64, BK=16, 256 threads, 4x4 outputs per thread.
// ---------------------------------------------------------------------------
template<int RELU>
__global__ __launch_bounds__(256) void gemm_kernel(const float* __restrict__ A,
                                                   const float* __restrict__ W,
                                                   const float* __restrict__ bias,
                                                   const float* res,
                                                   float* C,
                                                   int M, int N, int K) {
    __shared__ float As[16][64];   // [k][m]
    __shared__ float Ws[16][64];   // [k][n]
    int t  = threadIdx.x;
    int tx = t & 15, ty = t >> 4;
    int bm = blockIdx.y * 64, bn = blockIdx.x * 64;

    int ar = t >> 2;
    int ac = (t & 3) * 4;
    int wr = t >> 4;
    int wc = (t & 15) * 4;

    float acc[4][4] = {};

    for (int kt = 0; kt < K; kt += 16) {
        float4 av = *(const float4*)(A + (size_t)(bm + ar) * K + kt + ac);
        float4 wv = *(const float4*)(W + (size_t)(kt + wr) * N + bn + wc);
        __syncthreads();
        As[ac + 0][ar] = av.x;
        As[ac + 1][ar] = av.y;
        As[ac + 2][ar] = av.z;
        As[ac + 3][ar] = av.w;
        *(float4*)&Ws[wr][wc] = wv;
        __syncthreads();
        #pragma unroll
        for (int k = 0; k < 16; k++) {
            float4 a4 = *(const float4*)&As[k][ty * 4];
            float4 w4 = *(const float4*)&Ws[k][tx * 4];
            float a[4] = {a4.x, a4.y, a4.z, a4.w};
            float w[4] = {w4.x, w4.y, w4.z, w4.w};
            #pragma unroll
            for (int i = 0; i < 4; i++)
                #pragma unroll
                for (int j = 0; j < 4; j++)
                    acc[i][j] = fmaf(a[i], w[j], acc[i][j]);
        }
    }

    #pragma unroll
    for (int i = 0; i < 4; i++) {
        int r = bm + ty * 4 + i;
        #pragma unroll
        for (int j = 0; j < 4; j++) {
            int c = bn + tx * 4 + j;
            float v = acc[i][j] + bias[c];
            if (RELU) v = fmaxf(v, 0.0f);
            if (res) v += res[(size_t)r * N + c];
            C[(size_t)r * N + c] = v;
        }
    }
}

// ---------------------------------------------------------------------------
// Flash-style windowed-causal attention. One block per (b, h, 64-query tile).
// valid keys for q: [q-511, q]. Online softmax over 64-key tiles.
// LDS: sQ[q][d], sKV holds K^T[d][key] then V[key][d], sP[q][k].
// Thread map: 16x16 grid, each thread owns 4q x 4{k|d} register tile.
// Contraction reads are float4 contiguous-across-lanes => conflict-free.
// ---------------------------------------------------------------------------
__global__ __launch_bounds__(256) void flash_attn_kernel(const float* __restrict__ qkv,
                                                         const float* __restrict__ res_pos,
                                                         float* __restrict__ ctx) {
    int q0 = blockIdx.x * 64;
    int h  = blockIdx.y;
    int b  = blockIdx.z;
    int t  = threadIdx.x;
    int tx = t & 15, ty = t >> 4;
    int tx4 = tx * 4, ty4 = ty * 4;

    __shared__ float sQ[64][68];
    __shared__ float sKV[64][68];
    __shared__ float sP[64][68];
    __shared__ float sBias[R_];

    const size_t row3 = 3 * D_;
    const float* base = qkv + (size_t)b * L_ * row3;
    const int bL = b * L_;

    // stage Q tile [q][d]
    {
        int r = t >> 2, c0 = (t & 3) * 16;
        const float* src = base + (size_t)(q0 + r) * row3 + h * HD_ + c0;
        #pragma unroll
        for (int c = 0; c < 16; c += 4)
            *(float4*)&sQ[r][c0 + c] = *(const float4*)(src + c);
    }
    sBias[t]       = res_pos[h * R_ + t];
    sBias[t + 256] = res_pos[h * R_ + t + 256];

    float acc_o[4][4] = {};
    float m_i[4], l_i[4];
    #pragma unroll
    for (int i = 0; i < 4; i++) { m_i[i] = -1e30f; l_i[i] = 0.f; }

    int klo = q0 - (R_ - 1); if (klo < 0) klo = 0;
    int kt0 = klo & ~63;
    const float scale = 0.125f;   // 1/sqrt(64)

    for (int k0 = kt0; k0 <= q0; k0 += 64) {
        __syncthreads();   // prev-iter sKV(V)/sP readers done
        // stage K^T: sKV[d][key]
        {
            int r = t >> 2, c0 = (t & 3) * 16;
            const float* src = base + (size_t)(k0 + r) * row3 + D_ + h * HD_ + c0;
            #pragma unroll
            for (int c = 0; c < 16; c += 4) {
                float4 v = *(const float4*)(src + c);
                sKV[c0 + c + 0][r] = v.x;
                sKV[c0 + c + 1][r] = v.y;
                sKV[c0 + c + 2][r] = v.z;
                sKV[c0 + c + 3][r] = v.w;
            }
        }
        __syncthreads();

        // S = Q K^T  (contraction over d)
        float s[4][4] = {};
        #pragma unroll
        for (int dd = 0; dd < 64; dd += 4) {
            float aa[4][4], bb[4][4];
            #pragma unroll
            for (int i = 0; i < 4; i++)
                *(float4*)aa[i] = *(const float4*)&sQ[ty4 + i][dd];
            #pragma unroll
            for (int d2 = 0; d2 < 4; d2++)
                *(float4*)bb[d2] = *(const float4*)&sKV[dd + d2][tx4];
            #pragma unroll
            for (int i = 0; i < 4; i++)
                #pragma unroll
                for (int j = 0; j < 4; j++)
                    s[i][j] += aa[i][0]*bb[0][j] + aa[i][1]*bb[1][j]
                             + aa[i][2]*bb[2][j] + aa[i][3]*bb[3][j];
        }

        // mask + bias + online softmax; write P tile
        #pragma unroll
        for (int i = 0; i < 4; i++) {
            int q = q0 + ty4 + i;
            float rm = -1e30f;
            #pragma unroll
            for (int j = 0; j < 4; j++) {
                int key = k0 + tx4 + j;
                int diff = q - key;
                bool valid = (diff >= 0) && (diff < R_);
                int dc = diff < 0 ? 0 : (diff > R_ - 1 ? R_ - 1 : diff);
                float sv = valid ? s[i][j] * scale + sBias[dc] : -1e30f;
                s[i][j] = sv;
                rm = fmaxf(rm, sv);
            }
            #pragma unroll
            for (int o = 8; o > 0; o >>= 1) rm = fmaxf(rm, __shfl_xor(rm, o, 16));
            float mnew = fmaxf(m_i[i], rm);
            float alpha = __expf(m_i[i] - mnew);
            m_i[i] = mnew;
            float rsum = 0.f;
            #pragma unroll
            for (int j = 0; j < 4; j++) {
                float p = (s[i][j] > -1e29f) ? __expf(s[i][j] - mnew) : 0.f;
                s[i][j] = p;
                rsum += p;
            }
            #pragma unroll
            for (int o = 8; o > 0; o >>= 1) rsum += __shfl_xor(rsum, o, 16);
            l_i[i] = l_i[i] * alpha + rsum;
            #pragma unroll
            for (int j = 0; j < 4; j++) acc_o[i][j] *= alpha;
            *(float4*)&sP[ty4 + i][tx4] = *(const float4*)s[i];
        }
        __syncthreads();   // K reads + P writes done

        // stage V: sKV[key][d]
        {
            int r = t >> 2, c0 = (t & 3) * 16;
            const float* src = base + (size_t)(k0 + r) * row3 + 2 * D_ + h * HD_ + c0;
            #pragma unroll
            for (int c = 0; c < 16; c += 4)
                *(float4*)&sKV[r][c0 + c] = *(const float4*)(src + c);
        }
        __syncthreads();

        // O += P V  (contraction over k)
        #pragma unroll
        for (int kk = 0; kk < 64; kk += 4) {
            float pp[4][4], vv[4][4];
            #pragma unroll
            for (int i = 0; i < 4; i++)
                *(float4*)pp[i] = *(const float4*)&sP[ty4 + i][kk];
            #pragma unroll
            for (int k2 = 0; k2 < 4; k2++)
                *(float4*)vv[k2] = *(const float4*)&sKV[kk + k2][tx4];
            #pragma unroll
            for (int i = 0; i < 4; i++)
                #pragma unroll
                for (int j = 0; j < 4; j++)
                    acc_o[i][j] += pp[i][0]*vv[0][j] + pp[i][1]*vv[1][j]
                                 + pp[i][2]*vv[2][j] + pp[i][3]*vv[3][j];
        }
    }

    // normalize + write ctx[(b*L+q)][h*64+d]
    #pragma unroll
    for (int i = 0; i < 4; i++) {
        float invl = 1.0f / l_i[i];
        float4 o4;
        o4.x = acc_o[i][0] * invl;
        o4.y = acc_o[i][1] * invl;
        o4.z = acc_o[i][2] * invl;
        o4.w = acc_o[i][3] * invl;
        *(float4*)(ctx + (size_t)(bL + q0 + ty4 + i) * D_ + h * HD_ + tx4) = o4;
    }
}

// ---------------------------------------------------------------------------
// Orchestration.
// ws layout (floats): A[0, M*D) ; Bq[M*D, 4*M*D) ; extra[4*M*D, 5*M*D)
// ---------------------------------------------------------------------------
extern "C" void kernel_launch(void* const* d_in, const int* in_sizes, int n_in,
                              void* d_out, int out_size, void* d_ws, size_t ws_size,
                              hipStream_t stream) {
    const float* x      = (const float*)d_in[0];
    const float* res_pos= (const float*)d_in[1];
    const float* w_qkv  = (const float*)d_in[2];
    const float* b_qkv  = (const float*)d_in[3];
    const float* w_out  = (const float*)d_in[4];
    const float* b_out  = (const float*)d_in[5];
    const float* w1     = (const float*)d_in[6];
    const float* b1     = (const float*)d_in[7];
    const float* w2     = (const float*)d_in[8];
    const float* b2     = (const float*)d_in[9];
    const float* ln1_g  = (const float*)d_in[10];
    const float* ln1_b  = (const float*)d_in[11];
    const float* ln2_g  = (const float*)d_in[12];
    const float* ln2_b  = (const float*)d_in[13];
    float* out = (float*)d_out;
    float* ws  = (float*)d_ws;

    float* A  = ws;                      // M*D
    float* Bq = ws + (size_t)M_ * D_;    // M*3D (qkv)
    float* h1 = ws + (size_t)M_ * D_;    // M*4D (overlays Bq + extra)

    // 1. xn = LN1(x)
    ln_kernel<<<M_, 256, 0, stream>>>(x, ln1_g, ln1_b, A);
    // 2. qkv = xn @ w_qkv + b_qkv
    gemm_kernel<0><<<dim3(3 * D_ / 64, M_ / 64), 256, 0, stream>>>(
        A, w_qkv, b_qkv, nullptr, Bq, M_, 3 * D_, D_);
    // 3. ctx = flash windowed attention (writes into A)
    flash_attn_kernel<<<dim3(L_ / 64, H_, B_), 256, 0, stream>>>(Bq, res_pos, A);
    // 4. x1 = x + ctx @ w_out + b_out   (into d_out)
    gemm_kernel<0><<<dim3(D_ / 64, M_ / 64), 256, 0, stream>>>(
        A, w_out, b_out, x, out, M_, D_, D_);
    // 5. xn2 = LN2(x1)  (into A)
    ln_kernel<<<M_, 256, 0, stream>>>(out, ln2_g, ln2_b, A);
    // 6. h1 = relu(xn2 @ w1 + b1)
    gemm_kernel<1><<<dim3(4 * D_ / 64, M_ / 64), 256, 0, stream>>>(
        A, w1, b1, nullptr, h1, M_, 4 * D_, D_);
    // 7. out = x1 + h1 @ w2 + b2   (in-place residual on d_out)
    gemm_kernel<0><<<dim3(D_ / 64, M_ / 64), 256, 0, stream>>>(
        h1, w2, b2, out, out, M_, D_, 4 * D_);
}

// Round 3
// 1153.603 us; speedup vs baseline: 2.8113x; 1.9959x over previous
//
#include <hip/hip_runtime.h>
#include <math.h>

// Problem constants
#define B_  2
#define L_  2048
#define D_  1024
#define H_  16
#define R_  512
#define HD_ 64
#define M_  (B_*L_)          // 4096 rows
#define EPS_ 1e-5f

typedef __attribute__((ext_vector_type(8))) short bf16x8;
typedef __attribute__((ext_vector_type(4))) float f32x4;

// fp32 -> bf16 round-to-nearest-even (bit-level, avoids header type games)
__device__ __forceinline__ unsigned short f2bf(float f) {
    unsigned int u = __float_as_uint(f);
    u += 0x7fffu + ((u >> 16) & 1u);
    return (unsigned short)(u >> 16);
}

// async global->LDS, 16 bytes per lane. LDS dest must be wave-uniform base +
// lane*16 (our staging index t*16 satisfies this).
__device__ __forceinline__ void gl2lds16(const void* g, void* l) {
    __builtin_amdgcn_global_load_lds(
        (const __attribute__((address_space(1))) unsigned int*)g,
        (__attribute__((address_space(3))) unsigned int*)l, 16, 0, 0);
}

// ---------------------------------------------------------------------------
// LayerNorm: one block per row, fp32 in -> bf16 out (feeds MFMA GEMMs)
// ---------------------------------------------------------------------------
__global__ __launch_bounds__(256) void ln_kernel(const float* __restrict__ x,
                                                 const float* __restrict__ g,
                                                 const float* __restrict__ b,
                                                 unsigned short* __restrict__ out) {
    int row = blockIdx.x;
    int t = threadIdx.x;
    const float4* xr = (const float4*)(x + (size_t)row * D_);
    float4 v = xr[t];
    float s  = v.x + v.y + v.z + v.w;
    float ss = v.x*v.x + v.y*v.y + v.z*v.z + v.w*v.w;
    #pragma unroll
    for (int o = 32; o > 0; o >>= 1) {
        s  += __shfl_down(s,  o);
        ss += __shfl_down(ss, o);
    }
    __shared__ float rs[4], rss[4];
    int wave = t >> 6, lane = t & 63;
    if (lane == 0) { rs[wave] = s; rss[wave] = ss; }
    __syncthreads();
    if (t == 0) {
        float a = 0.f, c = 0.f;
        for (int i = 0; i < 4; i++) { a += rs[i]; c += rss[i]; }
        rs[0] = a; rss[0] = c;
    }
    __syncthreads();
    float mean = rs[0] * (1.0f / D_);
    float var  = rss[0] * (1.0f / D_) - mean * mean;
    float inv  = rsqrtf(var + EPS_);
    float4 gv = ((const float4*)g)[t];
    float4 bv = ((const float4*)b)[t];
    ushort4 ob;
    ob.x = f2bf((v.x - mean) * inv * gv.x + bv.x);
    ob.y = f2bf((v.y - mean) * inv * gv.y + bv.y);
    ob.z = f2bf((v.z - mean) * inv * gv.z + bv.z);
    ob.w = f2bf((v.w - mean) * inv * gv.w + bv.w);
    ((ushort4*)(out + (size_t)row * D_))[t] = ob;
}

// ---------------------------------------------------------------------------
// Weight transpose+convert: in[K][N] fp32 -> out[N][K] bf16 (32x32 LDS tiles)
// ---------------------------------------------------------------------------
__global__ __launch_bounds__(256) void wtrans_kernel(const float* __restrict__ in,
                                                     unsigned short* __restrict__ out,
                                                     int K, int N) {
    __shared__ float tile[32][33];
    int bn = blockIdx.x * 32, bk = blockIdx.y * 32;
    int t = threadIdx.x;
    int r = t >> 3, c4 = (t & 7) * 4;
    float4 v = *(const float4*)(in + (size_t)(bk + r) * N + bn + c4);
    tile[r][c4+0] = v.x; tile[r][c4+1] = v.y; tile[r][c4+2] = v.z; tile[r][c4+3] = v.w;
    __syncthreads();
    ushort4 o;
    o.x = f2bf(tile[c4+0][r]);
    o.y = f2bf(tile[c4+1][r]);
    o.z = f2bf(tile[c4+2][r]);
    o.w = f2bf(tile[c4+3][r]);
    *(ushort4*)(out + (size_t)(bn + r) * K + bk + c4) = o;
}

// ---------------------------------------------------------------------------
// bf16 MFMA GEMM (m97 structure): C[M,N] = A[M,K] @ Wt[N,K]^T + bias (+res)
// BM x 128 tile, BK=32, 4 waves in 2x2, each wave (BM/2)x64 via 16x16x32 MFMA.
// global_load_lds width-16 staging; ds_read_b128 fragments.
// C/D layout: col = lane&15, row = (lane>>4)*4 + reg   [verified m89/m91]
// ---------------------------------------------------------------------------
template<int BM, int RELU, int OUT_BF16>
__global__ __launch_bounds__(256) void gemm_mfma(const unsigned short* __restrict__ A,
                                                 const unsigned short* __restrict__ Wt,
                                                 const float* __restrict__ bias,
                                                 const float* __restrict__ res,
                                                 void* __restrict__ Cout,
                                                 int M, int N, int K) {
    constexpr int BN = 128, BK = 32;
    constexpr int TM = BM / 32;          // m-tiles per wave (128->4, 64->2)
    __shared__ __align__(16) unsigned short As[BM * BK];
    __shared__ __align__(16) unsigned short Bs[BN * BK];
    int t = threadIdx.x;
    int wave = t >> 6, lane = t & 63;
    int q = lane >> 4, cl = lane & 15;
    int bm = blockIdx.y * BM, bn = blockIdx.x * BN;
    int wm = (wave >> 1) * (BM / 2);
    int wn = (wave & 1) * 64;

    int sm = t >> 2;            // staging row (64 rows per 256-thread pass)
    int sc = (t & 3) * 8;       // staging col in bf16 elems (16B chunks)

    f32x4 acc[TM][4] = {};

    for (int kt = 0; kt < K; kt += BK) {
        __syncthreads();   // prev-iter LDS readers done
        #pragma unroll
        for (int s = 0; s < BM / 64; s++)
            gl2lds16(A + (size_t)(bm + s*64 + sm) * K + kt + sc,
                     &As[(s*64 + sm) * BK + sc]);
        #pragma unroll
        for (int s = 0; s < 2; s++)
            gl2lds16(Wt + (size_t)(bn + s*64 + sm) * K + kt + sc,
                     &Bs[(s*64 + sm) * BK + sc]);
        __syncthreads();   // drains vmcnt (compiler emits waitcnt before barrier)

        bf16x8 af[TM], bfr[4];
        #pragma unroll
        for (int i = 0; i < TM; i++)
            af[i] = *(const bf16x8*)&As[(wm + i*16 + cl) * BK + q*8];
        #pragma unroll
        for (int j = 0; j < 4; j++)
            bfr[j] = *(const bf16x8*)&Bs[(wn + j*16 + cl) * BK + q*8];
        #pragma unroll
        for (int i = 0; i < TM; i++)
            #pragma unroll
            for (int j = 0; j < 4; j++)
                acc[i][j] = __builtin_amdgcn_mfma_f32_16x16x32_bf16(
                                af[i], bfr[j], acc[i][j], 0, 0, 0);
    }

    #pragma unroll
    for (int i = 0; i < TM; i++) {
        #pragma unroll
        for (int j = 0; j < 4; j++) {
            #pragma unroll
            for (int r = 0; r < 4; r++) {
                int row = bm + wm + i*16 + q*4 + r;
                int col = bn + wn + j*16 + cl;
                float v = acc[i][j][r] + bias[col];
                if (RELU) v = fmaxf(v, 0.0f);
                if (res)  v += res[(size_t)row * N + col];
                if (OUT_BF16)
                    ((unsigned short*)Cout)[(size_t)row * N + col] = f2bf(v);
                else
                    ((float*)Cout)[(size_t)row * N + col] = v;
            }
        }
    }
}

// ---------------------------------------------------------------------------
// Flash-style windowed-causal attention (fp32, unchanged structure from R2;
// epilogue now emits bf16 ctx for the MFMA out-projection).
// ---------------------------------------------------------------------------
__global__ __launch_bounds__(256) void flash_attn_kernel(const float* __restrict__ qkv,
                                                         const float* __restrict__ res_pos,
                                                         unsigned short* __restrict__ ctx) {
    int q0 = blockIdx.x * 64;
    int h  = blockIdx.y;
    int b  = blockIdx.z;
    int t  = threadIdx.x;
    int tx = t & 15, ty = t >> 4;
    int tx4 = tx * 4, ty4 = ty * 4;

    __shared__ float sQ[64][68];
    __shared__ float sKV[64][68];
    __shared__ float sP[64][68];
    __shared__ float sBias[R_];

    const size_t row3 = 3 * D_;
    const float* base = qkv + (size_t)b * L_ * row3;
    const int bL = b * L_;

    {
        int r = t >> 2, c0 = (t & 3) * 16;
        const float* src = base + (size_t)(q0 + r) * row3 + h * HD_ + c0;
        #pragma unroll
        for (int c = 0; c < 16; c += 4)
            *(float4*)&sQ[r][c0 + c] = *(const float4*)(src + c);
    }
    sBias[t]       = res_pos[h * R_ + t];
    sBias[t + 256] = res_pos[h * R_ + t + 256];

    float acc_o[4][4] = {};
    float m_i[4], l_i[4];
    #pragma unroll
    for (int i = 0; i < 4; i++) { m_i[i] = -1e30f; l_i[i] = 0.f; }

    int klo = q0 - (R_ - 1); if (klo < 0) klo = 0;
    int kt0 = klo & ~63;
    const float scale = 0.125f;

    for (int k0 = kt0; k0 <= q0; k0 += 64) {
        __syncthreads();
        {
            int r = t >> 2, c0 = (t & 3) * 16;
            const float* src = base + (size_t)(k0 + r) * row3 + D_ + h * HD_ + c0;
            #pragma unroll
            for (int c = 0; c < 16; c += 4) {
                float4 v = *(const float4*)(src + c);
                sKV[c0 + c + 0][r] = v.x;
                sKV[c0 + c + 1][r] = v.y;
                sKV[c0 + c + 2][r] = v.z;
                sKV[c0 + c + 3][r] = v.w;
            }
        }
        __syncthreads();

        float s[4][4] = {};
        #pragma unroll
        for (int dd = 0; dd < 64; dd += 4) {
            float aa[4][4], bb[4][4];
            #pragma unroll
            for (int i = 0; i < 4; i++)
                *(float4*)aa[i] = *(const float4*)&sQ[ty4 + i][dd];
            #pragma unroll
            for (int d2 = 0; d2 < 4; d2++)
                *(float4*)bb[d2] = *(const float4*)&sKV[dd + d2][tx4];
            #pragma unroll
            for (int i = 0; i < 4; i++)
                #pragma unroll
                for (int j = 0; j < 4; j++)
                    s[i][j] += aa[i][0]*bb[0][j] + aa[i][1]*bb[1][j]
                             + aa[i][2]*bb[2][j] + aa[i][3]*bb[3][j];
        }

        #pragma unroll
        for (int i = 0; i < 4; i++) {
            int q = q0 + ty4 + i;
            float rm = -1e30f;
            #pragma unroll
            for (int j = 0; j < 4; j++) {
                int key = k0 + tx4 + j;
                int diff = q - key;
                bool valid = (diff >= 0) && (diff < R_);
                int dc = diff < 0 ? 0 : (diff > R_ - 1 ? R_ - 1 : diff);
                float sv = valid ? s[i][j] * scale + sBias[dc] : -1e30f;
                s[i][j] = sv;
                rm = fmaxf(rm, sv);
            }
            #pragma unroll
            for (int o = 8; o > 0; o >>= 1) rm = fmaxf(rm, __shfl_xor(rm, o, 16));
            float mnew = fmaxf(m_i[i], rm);
            float alpha = __expf(m_i[i] - mnew);
            m_i[i] = mnew;
            float rsum = 0.f;
            #pragma unroll
            for (int j = 0; j < 4; j++) {
                float p = (s[i][j] > -1e29f) ? __expf(s[i][j] - mnew) : 0.f;
                s[i][j] = p;
                rsum += p;
            }
            #pragma unroll
            for (int o = 8; o > 0; o >>= 1) rsum += __shfl_xor(rsum, o, 16);
            l_i[i] = l_i[i] * alpha + rsum;
            #pragma unroll
            for (int j = 0; j < 4; j++) acc_o[i][j] *= alpha;
            *(float4*)&sP[ty4 + i][tx4] = *(const float4*)s[i];
        }
        __syncthreads();

        {
            int r = t >> 2, c0 = (t & 3) * 16;
            const float* src = base + (size_t)(k0 + r) * row3 + 2 * D_ + h * HD_ + c0;
            #pragma unroll
            for (int c = 0; c < 16; c += 4)
                *(float4*)&sKV[r][c0 + c] = *(const float4*)(src + c);
        }
        __syncthreads();

        #pragma unroll
        for (int kk = 0; kk < 64; kk += 4) {
            float pp[4][4], vv[4][4];
            #pragma unroll
            for (int i = 0; i < 4; i++)
                *(float4*)pp[i] = *(const float4*)&sP[ty4 + i][kk];
            #pragma unroll
            for (int k2 = 0; k2 < 4; k2++)
                *(float4*)vv[k2] = *(const float4*)&sKV[kk + k2][tx4];
            #pragma unroll
            for (int i = 0; i < 4; i++)
                #pragma unroll
                for (int j = 0; j < 4; j++)
                    acc_o[i][j] += pp[i][0]*vv[0][j] + pp[i][1]*vv[1][j]
                                 + pp[i][2]*vv[2][j] + pp[i][3]*vv[3][j];
        }
    }

    #pragma unroll
    for (int i = 0; i < 4; i++) {
        float invl = 1.0f / l_i[i];
        ushort4 o4;
        o4.x = f2bf(acc_o[i][0] * invl);
        o4.y = f2bf(acc_o[i][1] * invl);
        o4.z = f2bf(acc_o[i][2] * invl);
        o4.w = f2bf(acc_o[i][3] * invl);
        *(ushort4*)(ctx + (size_t)(bL + q0 + ty4 + i) * D_ + h * HD_ + tx4) = o4;
    }
}

// ---------------------------------------------------------------------------
// Orchestration. ws layout (80 MB, proven available):
//   [ 0, 8M)  act_bf  : xn -> ctx -> xn2 (bf16, sequential lifetimes)
//   [ 8,14M)  wqkvT   : bf16 [3072][1024]
//   [14,16M)  woutT   : bf16 [1024][1024]
//   [16,24M)  w1T     : bf16 [4096][1024]
//   [24,32M)  w2T     : bf16 [1024][4096]
//   [32,80M)  qkv fp32 [4096][3072]; after attention reused for h1_bf (32 MB)
// ---------------------------------------------------------------------------
extern "C" void kernel_launch(void* const* d_in, const int* in_sizes, int n_in,
                              void* d_out, int out_size, void* d_ws, size_t ws_size,
                              hipStream_t stream) {
    const float* x      = (const float*)d_in[0];
    const float* res_pos= (const float*)d_in[1];
    const float* w_qkv  = (const float*)d_in[2];
    const float* b_qkv  = (const float*)d_in[3];
    const float* w_out  = (const float*)d_in[4];
    const float* b_out  = (const float*)d_in[5];
    const float* w1     = (const float*)d_in[6];
    const float* b1     = (const float*)d_in[7];
    const float* w2     = (const float*)d_in[8];
    const float* b2     = (const float*)d_in[9];
    const float* ln1_g  = (const float*)d_in[10];
    const float* ln1_b  = (const float*)d_in[11];
    const float* ln2_g  = (const float*)d_in[12];
    const float* ln2_b  = (const float*)d_in[13];
    float* out = (float*)d_out;
    char* ws = (char*)d_ws;

    unsigned short* act_bf = (unsigned short*)ws;
    unsigned short* wqkvT  = (unsigned short*)(ws + ((size_t)8  << 20));
    unsigned short* woutT  = (unsigned short*)(ws + ((size_t)14 << 20));
    unsigned short* w1T    = (unsigned short*)(ws + ((size_t)16 << 20));
    unsigned short* w2T    = (unsigned short*)(ws + ((size_t)24 << 20));
    float*          qkv    = (float*)         (ws + ((size_t)32 << 20));
    unsigned short* h1_bf  = (unsigned short*)(ws + ((size_t)32 << 20));

    // weight transpose+convert (fp32 [K][N] -> bf16 [N][K])
    wtrans_kernel<<<dim3(3072/32, 1024/32), 256, 0, stream>>>(w_qkv, wqkvT, 1024, 3072);
    wtrans_kernel<<<dim3(1024/32, 1024/32), 256, 0, stream>>>(w_out, woutT, 1024, 1024);
    wtrans_kernel<<<dim3(4096/32, 1024/32), 256, 0, stream>>>(w1,   w1T,   1024, 4096);
    wtrans_kernel<<<dim3(1024/32, 4096/32), 256, 0, stream>>>(w2,   w2T,   4096, 1024);

    // 1. xn = LN1(x) -> bf16
    ln_kernel<<<M_, 256, 0, stream>>>(x, ln1_g, ln1_b, act_bf);
    // 2. qkv = xn @ w_qkv + b_qkv -> fp32
    gemm_mfma<128,0,0><<<dim3(3072/128, M_/128), 256, 0, stream>>>(
        act_bf, wqkvT, b_qkv, nullptr, qkv, M_, 3072, 1024);
    // 3. ctx = windowed flash attention -> bf16
    flash_attn_kernel<<<dim3(L_/64, H_, B_), 256, 0, stream>>>(qkv, res_pos, act_bf);
    // 4. x1 = x + ctx @ w_out + b_out -> fp32 d_out
    gemm_mfma<64,0,0><<<dim3(1024/128, M_/64), 256, 0, stream>>>(
        act_bf, woutT, b_out, x, out, M_, 1024, 1024);
    // 5. xn2 = LN2(x1) -> bf16
    ln_kernel<<<M_, 256, 0, stream>>>(out, ln2_g, ln2_b, act_bf);
    // 6. h1 = relu(xn2 @ w1 + b1) -> bf16
    gemm_mfma<128,1,1><<<dim3(4096/128, M_/128), 256, 0, stream>>>(
        act_bf, w1T, b1, nullptr, h1_bf, M_, 4096, 1024);
    // 7. out = x1 + h1 @ w2 + b2 -> fp32 d_out (in-place residual)
    gemm_mfma<64,0,0><<<dim3(1024/128, M_/64), 256, 0, stream>>>(
        h1_bf, w2T, b2, out, out, M_, 1024, 4096);
}

// Round 4
// 385.206 us; speedup vs baseline: 8.4192x; 2.9948x over previous
//
#include <hip/hip_runtime.h>
#include <math.h>

// Problem constants
#define B_  2
#define L_  2048
#define D_  1024
#define H_  16
#define R_  512
#define HD_ 64
#define M_  (B_*L_)          // 4096 rows
#define EPS_ 1e-5f

typedef __attribute__((ext_vector_type(8))) short bf16x8;
typedef __attribute__((ext_vector_type(4))) float f32x4;

// fp32 -> bf16 round-to-nearest-even
__device__ __forceinline__ unsigned short f2bf(float f) {
    unsigned int u = __float_as_uint(f);
    u += 0x7fffu + ((u >> 16) & 1u);
    return (unsigned short)(u >> 16);
}

// async global->LDS, 16 bytes per lane (LDS dest = wave-uniform base + lane*16)
__device__ __forceinline__ void gl2lds16(const void* g, void* l) {
    __builtin_amdgcn_global_load_lds(
        (const __attribute__((address_space(1))) unsigned int*)g,
        (__attribute__((address_space(3))) unsigned int*)l, 16, 0, 0);
}

// ---------------------------------------------------------------------------
// LayerNorm: one block per row, fp32 in -> bf16 out
// ---------------------------------------------------------------------------
__global__ __launch_bounds__(256) void ln_kernel(const float* __restrict__ x,
                                                 const float* __restrict__ g,
                                                 const float* __restrict__ b,
                                                 unsigned short* __restrict__ out) {
    int row = blockIdx.x;
    int t = threadIdx.x;
    const float4* xr = (const float4*)(x + (size_t)row * D_);
    float4 v = xr[t];
    float s  = v.x + v.y + v.z + v.w;
    float ss = v.x*v.x + v.y*v.y + v.z*v.z + v.w*v.w;
    #pragma unroll
    for (int o = 32; o > 0; o >>= 1) {
        s  += __shfl_down(s,  o);
        ss += __shfl_down(ss, o);
    }
    __shared__ float rs[4], rss[4];
    int wave = t >> 6, lane = t & 63;
    if (lane == 0) { rs[wave] = s; rss[wave] = ss; }
    __syncthreads();
    if (t == 0) {
        float a = 0.f, c = 0.f;
        for (int i = 0; i < 4; i++) { a += rs[i]; c += rss[i]; }
        rs[0] = a; rss[0] = c;
    }
    __syncthreads();
    float mean = rs[0] * (1.0f / D_);
    float var  = rss[0] * (1.0f / D_) - mean * mean;
    float inv  = rsqrtf(var + EPS_);
    float4 gv = ((const float4*)g)[t];
    float4 bv = ((const float4*)b)[t];
    ushort4 ob;
    ob.x = f2bf((v.x - mean) * inv * gv.x + bv.x);
    ob.y = f2bf((v.y - mean) * inv * gv.y + bv.y);
    ob.z = f2bf((v.z - mean) * inv * gv.z + bv.z);
    ob.w = f2bf((v.w - mean) * inv * gv.w + bv.w);
    ((ushort4*)(out + (size_t)row * D_))[t] = ob;
}

// ---------------------------------------------------------------------------
// Weight transpose+convert: in[K][N] fp32 -> out[N][K] bf16
// ---------------------------------------------------------------------------
__global__ __launch_bounds__(256) void wtrans_kernel(const float* __restrict__ in,
                                                     unsigned short* __restrict__ out,
                                                     int K, int N) {
    __shared__ float tile[32][33];
    int bn = blockIdx.x * 32, bk = blockIdx.y * 32;
    int t = threadIdx.x;
    int r = t >> 3, c4 = (t & 7) * 4;
    float4 v = *(const float4*)(in + (size_t)(bk + r) * N + bn + c4);
    tile[r][c4+0] = v.x; tile[r][c4+1] = v.y; tile[r][c4+2] = v.z; tile[r][c4+3] = v.w;
    __syncthreads();
    ushort4 o;
    o.x = f2bf(tile[c4+0][r]);
    o.y = f2bf(tile[c4+1][r]);
    o.z = f2bf(tile[c4+2][r]);
    o.w = f2bf(tile[c4+3][r]);
    *(ushort4*)(out + (size_t)(bn + r) * K + bk + c4) = o;
}

// ---------------------------------------------------------------------------
// bf16 MFMA GEMM (m97 structure): C[M,N] = A[M,K] @ Wt[N,K]^T + bias (+res)
// C/D layout: col = lane&15, row = (lane>>4)*4 + reg
// ---------------------------------------------------------------------------
template<int BM, int RELU, int OUT_BF16>
__global__ __launch_bounds__(256) void gemm_mfma(const unsigned short* __restrict__ A,
                                                 const unsigned short* __restrict__ Wt,
                                                 const float* __restrict__ bias,
                                                 const float* __restrict__ res,
                                                 void* __restrict__ Cout,
                                                 int M, int N, int K) {
    constexpr int BN = 128, BK = 32;
    constexpr int TM = BM / 32;
    __shared__ __align__(16) unsigned short As[BM * BK];
    __shared__ __align__(16) unsigned short Bs[BN * BK];
    int t = threadIdx.x;
    int wave = t >> 6, lane = t & 63;
    int q = lane >> 4, cl = lane & 15;
    int bm = blockIdx.y * BM, bn = blockIdx.x * BN;
    int wm = (wave >> 1) * (BM / 2);
    int wn = (wave & 1) * 64;

    int sm = t >> 2;
    int sc = (t & 3) * 8;

    f32x4 acc[TM][4] = {};

    for (int kt = 0; kt < K; kt += BK) {
        __syncthreads();
        #pragma unroll
        for (int s = 0; s < BM / 64; s++)
            gl2lds16(A + (size_t)(bm + s*64 + sm) * K + kt + sc,
                     &As[(s*64 + sm) * BK + sc]);
        #pragma unroll
        for (int s = 0; s < 2; s++)
            gl2lds16(Wt + (size_t)(bn + s*64 + sm) * K + kt + sc,
                     &Bs[(s*64 + sm) * BK + sc]);
        __syncthreads();

        bf16x8 af[TM], bfr[4];
        #pragma unroll
        for (int i = 0; i < TM; i++)
            af[i] = *(const bf16x8*)&As[(wm + i*16 + cl) * BK + q*8];
        #pragma unroll
        for (int j = 0; j < 4; j++)
            bfr[j] = *(const bf16x8*)&Bs[(wn + j*16 + cl) * BK + q*8];
        #pragma unroll
        for (int i = 0; i < TM; i++)
            #pragma unroll
            for (int j = 0; j < 4; j++)
                acc[i][j] = __builtin_amdgcn_mfma_f32_16x16x32_bf16(
                                af[i], bfr[j], acc[i][j], 0, 0, 0);
    }

    #pragma unroll
    for (int i = 0; i < TM; i++) {
        #pragma unroll
        for (int j = 0; j < 4; j++) {
            #pragma unroll
            for (int r = 0; r < 4; r++) {
                int row = bm + wm + i*16 + q*4 + r;
                int col = bn + wn + j*16 + cl;
                float v = acc[i][j][r] + bias[col];
                if (RELU) v = fmaxf(v, 0.0f);
                if (res)  v += res[(size_t)row * N + col];
                if (OUT_BF16)
                    ((unsigned short*)Cout)[(size_t)row * N + col] = f2bf(v);
                else
                    ((float*)Cout)[(size_t)row * N + col] = v;
            }
        }
    }
}

// ---------------------------------------------------------------------------
// MFMA flash attention, windowed-causal (keys in [q-511, q]).
// One block per (b, h, 64-query tile); wave w owns queries [16w, 16w+16).
// LDS pitch 80 bf16 (160 B): b128 fragment reads hit all 32 banks evenly.
// sQP: Q tile (staged once, fragments hoisted to regs), then reused as P.
// sK: [key][d] row-major (B-operand of QK^T).
// sVt: [d][key] transposed (B-operand of PV), staged via packed-pair b32.
// ---------------------------------------------------------------------------
#define AP_ 80
__global__ __launch_bounds__(256) void attn_mfma_kernel(const unsigned short* __restrict__ qkv,
                                                        const float* __restrict__ res_pos,
                                                        unsigned short* __restrict__ ctx) {
    int q0 = blockIdx.x * 64;
    int h  = blockIdx.y;
    int b  = blockIdx.z;
    int t  = threadIdx.x;
    int w  = t >> 6, lane = t & 63;
    int quad = lane >> 4, cl = lane & 15;

    __shared__ __align__(16) unsigned short sQP[64 * AP_];
    __shared__ __align__(16) unsigned short sK [64 * AP_];
    __shared__ __align__(16) unsigned short sVt[64 * AP_];
    __shared__ float sBias[R_];

    const int bL = b * L_;
    const unsigned short* base = qkv + (size_t)bL * 3072;

    // stage Q tile [q][d] (rows q0..q0+63)
    #pragma unroll
    for (int c = t; c < 512; c += 256) {
        int row = c >> 3, off = (c & 7) * 8;
        uint4 v = *(const uint4*)(base + (size_t)(q0 + row) * 3072 + h * HD_ + off);
        *(uint4*)&sQP[row * AP_ + off] = v;
    }
    sBias[t]       = res_pos[h * R_ + t];
    sBias[t + 256] = res_pos[h * R_ + t + 256];
    __syncthreads();

    // hoist Q fragments: A-operand [m=cl][k=quad*8+j], two 32-wide k-steps
    bf16x8 qf0 = *(const bf16x8*)&sQP[(w*16 + cl) * AP_ + quad*8];
    bf16x8 qf1 = *(const bf16x8*)&sQP[(w*16 + cl) * AP_ + 32 + quad*8];

    f32x4 accO[4] = {};            // O[q][d], d-tiles j=0..3, C-layout
    float m_i[4], l_i[4];
    #pragma unroll
    for (int r = 0; r < 4; r++) { m_i[r] = -1e30f; l_i[r] = 0.f; }

    int klo = q0 - (R_ - 1); if (klo < 0) klo = 0;
    int kt0 = klo & ~63;
    const float scale = 0.125f;

    for (int k0 = kt0; k0 <= q0; k0 += 64) {
        __syncthreads();   // prev-iter readers of sK/sVt/sQP(P) done
        // stage K tile [key][d]
        #pragma unroll
        for (int c = t; c < 512; c += 256) {
            int row = c >> 3, off = (c & 7) * 8;
            uint4 v = *(const uint4*)(base + (size_t)(k0 + row) * 3072 + D_ + h * HD_ + off);
            *(uint4*)&sK[row * AP_ + off] = v;
        }
        // stage V transposed [d][key]: lane handles keys {2kp,2kp+1}, dims dg*8..+8
        {
            int kp = t & 31, dg = t >> 5;
            const unsigned short* v0 = base + (size_t)(k0 + 2*kp) * 3072 + 2*D_ + h * HD_ + dg*8;
            uint4 a4 = *(const uint4*)v0;
            uint4 b4 = *(const uint4*)(v0 + 3072);
            const unsigned short* pa = (const unsigned short*)&a4;
            const unsigned short* pb = (const unsigned short*)&b4;
            #pragma unroll
            for (int i = 0; i < 8; i++) {
                unsigned int packed = (unsigned int)pa[i] | ((unsigned int)pb[i] << 16);
                *(unsigned int*)&sVt[(dg*8 + i) * AP_ + 2*kp] = packed;
            }
        }
        __syncthreads();

        // S = Q K^T : 4 n-tiles x 2 k-steps
        f32x4 sacc[4] = {};
        #pragma unroll
        for (int j = 0; j < 4; j++) {
            bf16x8 kf0 = *(const bf16x8*)&sK[(j*16 + cl) * AP_ + quad*8];
            bf16x8 kf1 = *(const bf16x8*)&sK[(j*16 + cl) * AP_ + 32 + quad*8];
            sacc[j] = __builtin_amdgcn_mfma_f32_16x16x32_bf16(qf0, kf0, sacc[j], 0, 0, 0);
            sacc[j] = __builtin_amdgcn_mfma_f32_16x16x32_bf16(qf1, kf1, sacc[j], 0, 0, 0);
        }

        // online softmax per row r (row = quad*4+r in C-layout)
        float alpha[4];
        #pragma unroll
        for (int r = 0; r < 4; r++) {
            int qrow = q0 + w*16 + quad*4 + r;
            float sv[4];
            float rm = -1e30f;
            #pragma unroll
            for (int j = 0; j < 4; j++) {
                int key = k0 + j*16 + cl;
                int diff = qrow - key;
                bool valid = ((unsigned)diff) < (unsigned)R_;
                int dc = valid ? diff : 0;
                float x = fmaf(sacc[j][r], scale, sBias[dc]);
                sv[j] = valid ? x : -1e30f;
                rm = fmaxf(rm, sv[j]);
            }
            #pragma unroll
            for (int o = 8; o > 0; o >>= 1) rm = fmaxf(rm, __shfl_xor(rm, o));
            float mnew = fmaxf(m_i[r], rm);
            alpha[r] = __expf(m_i[r] - mnew);
            m_i[r] = mnew;
            float rsum = 0.f;
            #pragma unroll
            for (int j = 0; j < 4; j++) {
                float p = (sv[j] > -1e29f) ? __expf(sv[j] - mnew) : 0.f;
                sv[j] = p;
                rsum += p;
            }
            #pragma unroll
            for (int o = 8; o > 0; o >>= 1) rsum += __shfl_xor(rsum, o);
            l_i[r] = l_i[r] * alpha[r] + rsum;
            // write P (bf16) into sQP for the PV A-operand
            #pragma unroll
            for (int j = 0; j < 4; j++)
                sQP[(w*16 + quad*4 + r) * AP_ + j*16 + cl] = f2bf(sv[j]);
        }
        #pragma unroll
        for (int j = 0; j < 4; j++)
            #pragma unroll
            for (int r = 0; r < 4; r++)
                accO[j][r] *= alpha[r];
        __syncthreads();   // P writes visible

        // O += P V : A = P [q][key], B = V^T [d][key]
        bf16x8 pf0 = *(const bf16x8*)&sQP[(w*16 + cl) * AP_ + quad*8];
        bf16x8 pf1 = *(const bf16x8*)&sQP[(w*16 + cl) * AP_ + 32 + quad*8];
        #pragma unroll
        for (int j = 0; j < 4; j++) {
            bf16x8 vf0 = *(const bf16x8*)&sVt[(j*16 + cl) * AP_ + quad*8];
            bf16x8 vf1 = *(const bf16x8*)&sVt[(j*16 + cl) * AP_ + 32 + quad*8];
            accO[j] = __builtin_amdgcn_mfma_f32_16x16x32_bf16(pf0, vf0, accO[j], 0, 0, 0);
            accO[j] = __builtin_amdgcn_mfma_f32_16x16x32_bf16(pf1, vf1, accO[j], 0, 0, 0);
        }
    }

    // epilogue: normalize, write ctx bf16 [row][h*64+d]
    #pragma unroll
    for (int r = 0; r < 4; r++) {
        float inv = 1.0f / l_i[r];
        int row = bL + q0 + w*16 + quad*4 + r;
        #pragma unroll
        for (int j = 0; j < 4; j++)
            ctx[(size_t)row * D_ + h * HD_ + j*16 + cl] = f2bf(accO[j][r] * inv);
    }
}

// ---------------------------------------------------------------------------
// Orchestration. ws layout:
//   [ 0, 8M)  act_bf  : xn -> ctx -> xn2 (bf16)
//   [ 8,14M)  wqkvT   : bf16 [3072][1024]
//   [14,16M)  woutT   : bf16 [1024][1024]
//   [16,24M)  w1T     : bf16 [4096][1024]
//   [24,32M)  w2T     : bf16 [1024][4096]
//   [32,56M)  qkv_bf  : bf16 [4096][3072]; overlapped later by h1_bf [32,64M)
// ---------------------------------------------------------------------------
extern "C" void kernel_launch(void* const* d_in, const int* in_sizes, int n_in,
                              void* d_out, int out_size, void* d_ws, size_t ws_size,
                              hipStream_t stream) {
    const float* x      = (const float*)d_in[0];
    const float* res_pos= (const float*)d_in[1];
    const float* w_qkv  = (const float*)d_in[2];
    const float* b_qkv  = (const float*)d_in[3];
    const float* w_out  = (const float*)d_in[4];
    const float* b_out  = (const float*)d_in[5];
    const float* w1     = (const float*)d_in[6];
    const float* b1     = (const float*)d_in[7];
    const float* w2     = (const float*)d_in[8];
    const float* b2     = (const float*)d_in[9];
    const float* ln1_g  = (const float*)d_in[10];
    const float* ln1_b  = (const float*)d_in[11];
    const float* ln2_g  = (const float*)d_in[12];
    const float* ln2_b  = (const float*)d_in[13];
    float* out = (float*)d_out;
    char* ws = (char*)d_ws;

    unsigned short* act_bf = (unsigned short*)ws;
    unsigned short* wqkvT  = (unsigned short*)(ws + ((size_t)8  << 20));
    unsigned short* woutT  = (unsigned short*)(ws + ((size_t)14 << 20));
    unsigned short* w1T    = (unsigned short*)(ws + ((size_t)16 << 20));
    unsigned short* w2T    = (unsigned short*)(ws + ((size_t)24 << 20));
    unsigned short* qkv_bf = (unsigned short*)(ws + ((size_t)32 << 20));
    unsigned short* h1_bf  = (unsigned short*)(ws + ((size_t)32 << 20));

    // weight transpose+convert (fp32 [K][N] -> bf16 [N][K])
    wtrans_kernel<<<dim3(3072/32, 1024/32), 256, 0, stream>>>(w_qkv, wqkvT, 1024, 3072);
    wtrans_kernel<<<dim3(1024/32, 1024/32), 256, 0, stream>>>(w_out, woutT, 1024, 1024);
    wtrans_kernel<<<dim3(4096/32, 1024/32), 256, 0, stream>>>(w1,   w1T,   1024, 4096);
    wtrans_kernel<<<dim3(1024/32, 4096/32), 256, 0, stream>>>(w2,   w2T,   4096, 1024);

    // 1. xn = LN1(x) -> bf16
    ln_kernel<<<M_, 256, 0, stream>>>(x, ln1_g, ln1_b, act_bf);
    // 2. qkv = xn @ w_qkv + b_qkv -> bf16
    gemm_mfma<128,0,1><<<dim3(3072/128, M_/128), 256, 0, stream>>>(
        act_bf, wqkvT, b_qkv, nullptr, qkv_bf, M_, 3072, 1024);
    // 3. ctx = MFMA windowed flash attention -> bf16
    attn_mfma_kernel<<<dim3(L_/64, H_, B_), 256, 0, stream>>>(qkv_bf, res_pos, act_bf);
    // 4. x1 = x + ctx @ w_out + b_out -> fp32 d_out
    gemm_mfma<64,0,0><<<dim3(1024/128, M_/64), 256, 0, stream>>>(
        act_bf, woutT, b_out, x, out, M_, 1024, 1024);
    // 5. xn2 = LN2(x1) -> bf16
    ln_kernel<<<M_, 256, 0, stream>>>(out, ln2_g, ln2_b, act_bf);
    // 6. h1 = relu(xn2 @ w1 + b1) -> bf16
    gemm_mfma<128,1,1><<<dim3(4096/128, M_/128), 256, 0, stream>>>(
        act_bf, w1T, b1, nullptr, h1_bf, M_, 4096, 1024);
    // 7. out = x1 + h1 @ w2 + b2 -> fp32 d_out (in-place residual)
    gemm_mfma<64,0,0><<<dim3(1024/128, M_/64), 256, 0, stream>>>(
        h1_bf, w2T, b2, out, out, M_, 1024, 4096);
}

// Round 5
// 367.685 us; speedup vs baseline: 8.8203x; 1.0477x over previous
//
#include <hip/hip_runtime.h>
#include <math.h>

// Problem constants
#define B_  2
#define L_  2048
#define D_  1024
#define H_  16
#define R_  512
#define HD_ 64
#define M_  (B_*L_)          // 4096 rows
#define EPS_ 1e-5f

typedef __attribute__((ext_vector_type(8))) short bf16x8;
typedef __attribute__((ext_vector_type(4))) float f32x4;

// fp32 -> bf16 round-to-nearest-even
__device__ __forceinline__ unsigned short f2bf(float f) {
    unsigned int u = __float_as_uint(f);
    u += 0x7fffu + ((u >> 16) & 1u);
    return (unsigned short)(u >> 16);
}

// async global->LDS, 16 bytes per lane (LDS dest = wave-uniform base + lane*16)
__device__ __forceinline__ void gl2lds16(const void* g, void* l) {
    __builtin_amdgcn_global_load_lds(
        (const __attribute__((address_space(1))) unsigned int*)g,
        (__attribute__((address_space(3))) unsigned int*)l, 16, 0, 0);
}

// ---------------------------------------------------------------------------
// LayerNorm: one block per row, fp32 in -> bf16 out
// ---------------------------------------------------------------------------
__global__ __launch_bounds__(256) void ln_kernel(const float* __restrict__ x,
                                                 const float* __restrict__ g,
                                                 const float* __restrict__ b,
                                                 unsigned short* __restrict__ out) {
    int row = blockIdx.x;
    int t = threadIdx.x;
    const float4* xr = (const float4*)(x + (size_t)row * D_);
    float4 v = xr[t];
    float s  = v.x + v.y + v.z + v.w;
    float ss = v.x*v.x + v.y*v.y + v.z*v.z + v.w*v.w;
    #pragma unroll
    for (int o = 32; o > 0; o >>= 1) {
        s  += __shfl_down(s,  o);
        ss += __shfl_down(ss, o);
    }
    __shared__ float rs[4], rss[4];
    int wave = t >> 6, lane = t & 63;
    if (lane == 0) { rs[wave] = s; rss[wave] = ss; }
    __syncthreads();
    if (t == 0) {
        float a = 0.f, c = 0.f;
        for (int i = 0; i < 4; i++) { a += rs[i]; c += rss[i]; }
        rs[0] = a; rss[0] = c;
    }
    __syncthreads();
    float mean = rs[0] * (1.0f / D_);
    float var  = rss[0] * (1.0f / D_) - mean * mean;
    float inv  = rsqrtf(var + EPS_);
    float4 gv = ((const float4*)g)[t];
    float4 bv = ((const float4*)b)[t];
    ushort4 ob;
    ob.x = f2bf((v.x - mean) * inv * gv.x + bv.x);
    ob.y = f2bf((v.y - mean) * inv * gv.y + bv.y);
    ob.z = f2bf((v.z - mean) * inv * gv.z + bv.z);
    ob.w = f2bf((v.w - mean) * inv * gv.w + bv.w);
    ((ushort4*)(out + (size_t)row * D_))[t] = ob;
}

// ---------------------------------------------------------------------------
// Weight transpose+convert: in[K][N] fp32 -> out[N][K] bf16
// ---------------------------------------------------------------------------
__global__ __launch_bounds__(256) void wtrans_kernel(const float* __restrict__ in,
                                                     unsigned short* __restrict__ out,
                                                     int K, int N) {
    __shared__ float tile[32][33];
    int bn = blockIdx.x * 32, bk = blockIdx.y * 32;
    int t = threadIdx.x;
    int r = t >> 3, c4 = (t & 7) * 4;
    float4 v = *(const float4*)(in + (size_t)(bk + r) * N + bn + c4);
    tile[r][c4+0] = v.x; tile[r][c4+1] = v.y; tile[r][c4+2] = v.z; tile[r][c4+3] = v.w;
    __syncthreads();
    ushort4 o;
    o.x = f2bf(tile[c4+0][r]);
    o.y = f2bf(tile[c4+1][r]);
    o.z = f2bf(tile[c4+2][r]);
    o.w = f2bf(tile[c4+3][r]);
    *(ushort4*)(out + (size_t)(bn + r) * K + bk + c4) = o;
}

// ---------------------------------------------------------------------------
// bf16 MFMA GEMM: C[M,N] = A[M,K] @ Wt[N,K]^T + bias (+res)
// BM x 128 tile, BK = KSPLIT*32. KSPLIT>1 stages multiple sequential
// 32-wide m97-style sub-tiles (keeps global_load_lds contiguity AND the
// m97 pitch-32 bank pattern) -> KSPLIT x more MFMA per barrier pair.
// Grid is transposed (x = bm-fastest): consecutive blocks share the same
// B-stripe (the many-times-re-read operand) for L2 locality under
// round-robin XCD dispatch.
// C/D layout: col = lane&15, row = (lane>>4)*4 + reg
// ---------------------------------------------------------------------------
template<int BM, int KSPLIT, int RELU, int OUT_BF16>
__global__ __launch_bounds__(256) void gemm_mfma(const unsigned short* __restrict__ A,
                                                 const unsigned short* __restrict__ Wt,
                                                 const float* __restrict__ bias,
                                                 const float* __restrict__ res,
                                                 void* __restrict__ Cout,
                                                 int M, int N, int K) {
    constexpr int BN = 128;
    constexpr int BK = KSPLIT * 32;
    constexpr int TM = BM / 32;
    __shared__ __align__(16) unsigned short As[KSPLIT * BM * 32];
    __shared__ __align__(16) unsigned short Bs[KSPLIT * BN * 32];
    int t = threadIdx.x;
    int wave = t >> 6, lane = t & 63;
    int q = lane >> 4, cl = lane & 15;
    int bm = blockIdx.x * BM, bn = blockIdx.y * BN;   // transposed grid
    int wm = (wave >> 1) * (BM / 2);
    int wn = (wave & 1) * 64;

    int sm = t >> 2;            // staging row (64 rows per 256-thread pass)
    int sc = (t & 3) * 8;       // staging col in bf16 elems (16B chunks)

    f32x4 acc[TM][4] = {};

    for (int kt = 0; kt < K; kt += BK) {
        __syncthreads();
        #pragma unroll
        for (int hh = 0; hh < KSPLIT; hh++) {
            #pragma unroll
            for (int s = 0; s < BM / 64; s++)
                gl2lds16(A + (size_t)(bm + s*64 + sm) * K + kt + hh*32 + sc,
                         &As[hh * BM * 32 + (s*64 + sm) * 32 + sc]);
            #pragma unroll
            for (int s = 0; s < 2; s++)
                gl2lds16(Wt + (size_t)(bn + s*64 + sm) * K + kt + hh*32 + sc,
                         &Bs[hh * BN * 32 + (s*64 + sm) * 32 + sc]);
        }
        __syncthreads();

        #pragma unroll
        for (int hh = 0; hh < KSPLIT; hh++) {
            bf16x8 af[TM], bfr[4];
            #pragma unroll
            for (int i = 0; i < TM; i++)
                af[i] = *(const bf16x8*)&As[hh * BM * 32 + (wm + i*16 + cl) * 32 + q*8];
            #pragma unroll
            for (int j = 0; j < 4; j++)
                bfr[j] = *(const bf16x8*)&Bs[hh * BN * 32 + (wn + j*16 + cl) * 32 + q*8];
            #pragma unroll
            for (int i = 0; i < TM; i++)
                #pragma unroll
                for (int j = 0; j < 4; j++)
                    acc[i][j] = __builtin_amdgcn_mfma_f32_16x16x32_bf16(
                                    af[i], bfr[j], acc[i][j], 0, 0, 0);
        }
    }

    #pragma unroll
    for (int i = 0; i < TM; i++) {
        #pragma unroll
        for (int j = 0; j < 4; j++) {
            #pragma unroll
            for (int r = 0; r < 4; r++) {
                int row = bm + wm + i*16 + q*4 + r;
                int col = bn + wn + j*16 + cl;
                float v = acc[i][j][r] + bias[col];
                if (RELU) v = fmaxf(v, 0.0f);
                if (res)  v += res[(size_t)row * N + col];
                if (OUT_BF16)
                    ((unsigned short*)Cout)[(size_t)row * N + col] = f2bf(v);
                else
                    ((float*)Cout)[(size_t)row * N + col] = v;
            }
        }
    }
}

// ---------------------------------------------------------------------------
// MFMA flash attention, windowed-causal (keys in [q-511, q]).
// ---------------------------------------------------------------------------
#define AP_ 80
__global__ __launch_bounds__(256) void attn_mfma_kernel(const unsigned short* __restrict__ qkv,
                                                        const float* __restrict__ res_pos,
                                                        unsigned short* __restrict__ ctx) {
    int q0 = blockIdx.x * 64;
    int h  = blockIdx.y;
    int b  = blockIdx.z;
    int t  = threadIdx.x;
    int w  = t >> 6, lane = t & 63;
    int quad = lane >> 4, cl = lane & 15;

    __shared__ __align__(16) unsigned short sQP[64 * AP_];
    __shared__ __align__(16) unsigned short sK [64 * AP_];
    __shared__ __align__(16) unsigned short sVt[64 * AP_];
    __shared__ float sBias[R_];

    const int bL = b * L_;
    const unsigned short* base = qkv + (size_t)bL * 3072;

    #pragma unroll
    for (int c = t; c < 512; c += 256) {
        int row = c >> 3, off = (c & 7) * 8;
        uint4 v = *(const uint4*)(base + (size_t)(q0 + row) * 3072 + h * HD_ + off);
        *(uint4*)&sQP[row * AP_ + off] = v;
    }
    sBias[t]       = res_pos[h * R_ + t];
    sBias[t + 256] = res_pos[h * R_ + t + 256];
    __syncthreads();

    bf16x8 qf0 = *(const bf16x8*)&sQP[(w*16 + cl) * AP_ + quad*8];
    bf16x8 qf1 = *(const bf16x8*)&sQP[(w*16 + cl) * AP_ + 32 + quad*8];

    f32x4 accO[4] = {};
    float m_i[4], l_i[4];
    #pragma unroll
    for (int r = 0; r < 4; r++) { m_i[r] = -1e30f; l_i[r] = 0.f; }

    int klo = q0 - (R_ - 1); if (klo < 0) klo = 0;
    int kt0 = klo & ~63;
    const float scale = 0.125f;

    for (int k0 = kt0; k0 <= q0; k0 += 64) {
        __syncthreads();
        #pragma unroll
        for (int c = t; c < 512; c += 256) {
            int row = c >> 3, off = (c & 7) * 8;
            uint4 v = *(const uint4*)(base + (size_t)(k0 + row) * 3072 + D_ + h * HD_ + off);
            *(uint4*)&sK[row * AP_ + off] = v;
        }
        {
            int kp = t & 31, dg = t >> 5;
            const unsigned short* v0 = base + (size_t)(k0 + 2*kp) * 3072 + 2*D_ + h * HD_ + dg*8;
            uint4 a4 = *(const uint4*)v0;
            uint4 b4 = *(const uint4*)(v0 + 3072);
            const unsigned short* pa = (const unsigned short*)&a4;
            const unsigned short* pb = (const unsigned short*)&b4;
            #pragma unroll
            for (int i = 0; i < 8; i++) {
                unsigned int packed = (unsigned int)pa[i] | ((unsigned int)pb[i] << 16);
                *(unsigned int*)&sVt[(dg*8 + i) * AP_ + 2*kp] = packed;
            }
        }
        __syncthreads();

        f32x4 sacc[4] = {};
        #pragma unroll
        for (int j = 0; j < 4; j++) {
            bf16x8 kf0 = *(const bf16x8*)&sK[(j*16 + cl) * AP_ + quad*8];
            bf16x8 kf1 = *(const bf16x8*)&sK[(j*16 + cl) * AP_ + 32 + quad*8];
            sacc[j] = __builtin_amdgcn_mfma_f32_16x16x32_bf16(qf0, kf0, sacc[j], 0, 0, 0);
            sacc[j] = __builtin_amdgcn_mfma_f32_16x16x32_bf16(qf1, kf1, sacc[j], 0, 0, 0);
        }

        float alpha[4];
        #pragma unroll
        for (int r = 0; r < 4; r++) {
            int qrow = q0 + w*16 + quad*4 + r;
            float sv[4];
            float rm = -1e30f;
            #pragma unroll
            for (int j = 0; j < 4; j++) {
                int key = k0 + j*16 + cl;
                int diff = qrow - key;
                bool valid = ((unsigned)diff) < (unsigned)R_;
                int dc = valid ? diff : 0;
                float x = fmaf(sacc[j][r], scale, sBias[dc]);
                sv[j] = valid ? x : -1e30f;
                rm = fmaxf(rm, sv[j]);
            }
            #pragma unroll
            for (int o = 8; o > 0; o >>= 1) rm = fmaxf(rm, __shfl_xor(rm, o));
            float mnew = fmaxf(m_i[r], rm);
            alpha[r] = __expf(m_i[r] - mnew);
            m_i[r] = mnew;
            float rsum = 0.f;
            #pragma unroll
            for (int j = 0; j < 4; j++) {
                float p = (sv[j] > -1e29f) ? __expf(sv[j] - mnew) : 0.f;
                sv[j] = p;
                rsum += p;
            }
            #pragma unroll
            for (int o = 8; o > 0; o >>= 1) rsum += __shfl_xor(rsum, o);
            l_i[r] = l_i[r] * alpha[r] + rsum;
            #pragma unroll
            for (int j = 0; j < 4; j++)
                sQP[(w*16 + quad*4 + r) * AP_ + j*16 + cl] = f2bf(sv[j]);
        }
        #pragma unroll
        for (int j = 0; j < 4; j++)
            #pragma unroll
            for (int r = 0; r < 4; r++)
                accO[j][r] *= alpha[r];
        __syncthreads();

        bf16x8 pf0 = *(const bf16x8*)&sQP[(w*16 + cl) * AP_ + quad*8];
        bf16x8 pf1 = *(const bf16x8*)&sQP[(w*16 + cl) * AP_ + 32 + quad*8];
        #pragma unroll
        for (int j = 0; j < 4; j++) {
            bf16x8 vf0 = *(const bf16x8*)&sVt[(j*16 + cl) * AP_ + quad*8];
            bf16x8 vf1 = *(const bf16x8*)&sVt[(j*16 + cl) * AP_ + 32 + quad*8];
            accO[j] = __builtin_amdgcn_mfma_f32_16x16x32_bf16(pf0, vf0, accO[j], 0, 0, 0);
            accO[j] = __builtin_amdgcn_mfma_f32_16x16x32_bf16(pf1, vf1, accO[j], 0, 0, 0);
        }
    }

    #pragma unroll
    for (int r = 0; r < 4; r++) {
        float inv = 1.0f / l_i[r];
        int row = bL + q0 + w*16 + quad*4 + r;
        #pragma unroll
        for (int j = 0; j < 4; j++)
            ctx[(size_t)row * D_ + h * HD_ + j*16 + cl] = f2bf(accO[j][r] * inv);
    }
}

// ---------------------------------------------------------------------------
// Orchestration. ws layout:
//   [ 0, 8M)  act_bf  : xn -> ctx -> xn2 (bf16)
//   [ 8,14M)  wqkvT   : bf16 [3072][1024]
//   [14,16M)  woutT   : bf16 [1024][1024]
//   [16,24M)  w1T     : bf16 [4096][1024]
//   [24,32M)  w2T     : bf16 [1024][4096]
//   [32,56M)  qkv_bf  : bf16 [4096][3072]; overlapped later by h1_bf [32,64M)
// ---------------------------------------------------------------------------
extern "C" void kernel_launch(void* const* d_in, const int* in_sizes, int n_in,
                              void* d_out, int out_size, void* d_ws, size_t ws_size,
                              hipStream_t stream) {
    const float* x      = (const float*)d_in[0];
    const float* res_pos= (const float*)d_in[1];
    const float* w_qkv  = (const float*)d_in[2];
    const float* b_qkv  = (const float*)d_in[3];
    const float* w_out  = (const float*)d_in[4];
    const float* b_out  = (const float*)d_in[5];
    const float* w1     = (const float*)d_in[6];
    const float* b1     = (const float*)d_in[7];
    const float* w2     = (const float*)d_in[8];
    const float* b2     = (const float*)d_in[9];
    const float* ln1_g  = (const float*)d_in[10];
    const float* ln1_b  = (const float*)d_in[11];
    const float* ln2_g  = (const float*)d_in[12];
    const float* ln2_b  = (const float*)d_in[13];
    float* out = (float*)d_out;
    char* ws = (char*)d_ws;

    unsigned short* act_bf = (unsigned short*)ws;
    unsigned short* wqkvT  = (unsigned short*)(ws + ((size_t)8  << 20));
    unsigned short* woutT  = (unsigned short*)(ws + ((size_t)14 << 20));
    unsigned short* w1T    = (unsigned short*)(ws + ((size_t)16 << 20));
    unsigned short* w2T    = (unsigned short*)(ws + ((size_t)24 << 20));
    unsigned short* qkv_bf = (unsigned short*)(ws + ((size_t)32 << 20));
    unsigned short* h1_bf  = (unsigned short*)(ws + ((size_t)32 << 20));

    // weight transpose+convert (fp32 [K][N] -> bf16 [N][K])
    wtrans_kernel<<<dim3(3072/32, 1024/32), 256, 0, stream>>>(w_qkv, wqkvT, 1024, 3072);
    wtrans_kernel<<<dim3(1024/32, 1024/32), 256, 0, stream>>>(w_out, woutT, 1024, 1024);
    wtrans_kernel<<<dim3(4096/32, 1024/32), 256, 0, stream>>>(w1,   w1T,   1024, 4096);
    wtrans_kernel<<<dim3(1024/32, 4096/32), 256, 0, stream>>>(w2,   w2T,   4096, 1024);

    // 1. xn = LN1(x) -> bf16
    ln_kernel<<<M_, 256, 0, stream>>>(x, ln1_g, ln1_b, act_bf);
    // 2. qkv = xn @ w_qkv + b_qkv -> bf16   (grid transposed: x=bm)
    gemm_mfma<128,1,0,1><<<dim3(M_/128, 3072/128), 256, 0, stream>>>(
        act_bf, wqkvT, b_qkv, nullptr, qkv_bf, M_, 3072, 1024);
    // 3. ctx = MFMA windowed flash attention -> bf16
    attn_mfma_kernel<<<dim3(L_/64, H_, B_), 256, 0, stream>>>(qkv_bf, res_pos, act_bf);
    // 4. x1 = x + ctx @ w_out + b_out -> fp32 d_out
    gemm_mfma<64,1,0,0><<<dim3(M_/64, 1024/128), 256, 0, stream>>>(
        act_bf, woutT, b_out, x, out, M_, 1024, 1024);
    // 5. xn2 = LN2(x1) -> bf16
    ln_kernel<<<M_, 256, 0, stream>>>(out, ln2_g, ln2_b, act_bf);
    // 6. h1 = relu(xn2 @ w1 + b1) -> bf16
    gemm_mfma<128,1,1,1><<<dim3(M_/128, 4096/128), 256, 0, stream>>>(
        act_bf, w1T, b1, nullptr, h1_bf, M_, 4096, 1024);
    // 7. out = x1 + h1 @ w2 + b2 -> fp32 d_out (KSPLIT=2: 16 MFMA/wave/barrier)
    gemm_mfma<64,2,0,0><<<dim3(M_/64, 1024/128), 256, 0, stream>>>(
        h1_bf, w2T, b2, out, out, M_, 1024, 4096);
}